// Round 9
// baseline (118.545 us; speedup 1.0000x reference)
//
#include <hip/hip_runtime.h>
#include <hip/hip_bf16.h>
#include <math.h>

typedef _Float16 f16;
typedef __attribute__((ext_vector_type(8))) _Float16 f16x8;
typedef __attribute__((ext_vector_type(4))) _Float16 f16x4;
typedef __attribute__((ext_vector_type(4))) float f32x4;

#define M_TOT 8192      // BATCH*SEQ
#define E_DIM 1024
#define F_DIM 4096
#define NQ    16

#define BARRIER() asm volatile("s_barrier" ::: "memory")
#define WAITV(n)  asm volatile("s_waitcnt vmcnt(" #n ")" ::: "memory")
#define WAITLGKM() asm volatile("s_waitcnt lgkmcnt(0)" ::: "memory")

__device__ __forceinline__ f16x8 cvt8(float4 a, float4 b) {
    f16x8 o;
    o[0] = (f16)a.x; o[1] = (f16)a.y; o[2] = (f16)a.z; o[3] = (f16)a.w;
    o[4] = (f16)b.x; o[5] = (f16)b.y; o[6] = (f16)b.z; o[7] = (f16)b.w;
    return o;
}

// ---------------- merged prep: W1 transpose-cast | Wo cast | W2 pad ----------------
__global__ __launch_bounds__(256) void prep_kernel(
    const float* __restrict__ W1, f16* __restrict__ W1t,
    const float* __restrict__ wo, f16* __restrict__ woh,
    const float* __restrict__ W2, f16* __restrict__ w2p)
{
    __shared__ float ls[64][68];
    const int b = blockIdx.x;
    if (b < 1024) {
        const int bf = b & 63;
        const int be = b >> 6;
        const int t  = threadIdx.x;
        const int r  = t >> 4;
        const int c4 = (t & 15) * 4;
        #pragma unroll
        for (int i = 0; i < 4; ++i) {
            int fr = r + i * 16;
            float4 v = *reinterpret_cast<const float4*>(W1 + (size_t)(bf * 64 + fr) * E_DIM + be * 64 + c4);
            ls[fr][c4] = v.x; ls[fr][c4 + 1] = v.y; ls[fr][c4 + 2] = v.z; ls[fr][c4 + 3] = v.w;
        }
        __syncthreads();
        const int er = t >> 2;
        const int fc = (t & 3) * 16;
        f16x8 o0, o1;
        #pragma unroll
        for (int j = 0; j < 8; ++j) { o0[j] = (f16)ls[fc + j][er]; o1[j] = (f16)ls[fc + 8 + j][er]; }
        f16* dst = W1t + (size_t)(be * 64 + er) * F_DIM + bf * 64 + fc;
        *reinterpret_cast<f16x8*>(dst)     = o0;
        *reinterpret_cast<f16x8*>(dst + 8) = o1;
    } else if (b < 3072) {
        size_t i = ((size_t)(b - 1024) * 256 + threadIdx.x) * 8;
        float4 v0 = *reinterpret_cast<const float4*>(wo + i);
        float4 v1 = *reinterpret_cast<const float4*>(wo + i + 4);
        *reinterpret_cast<f16x8*>(woh + i) = cvt8(v0, v1);
    } else {
        int t = (b - 3072) * 256 + threadIdx.x;
        size_t i = (size_t)t * 8;
        int col = (int)(i & 31);
        f16x8 o;
        if (col < NQ) {
            int row = (int)(i >> 5);
            float4 v0 = *reinterpret_cast<const float4*>(W2 + (size_t)row * NQ + col);
            float4 v1 = *reinterpret_cast<const float4*>(W2 + (size_t)row * NQ + col + 4);
            o = cvt8(v0, v1);
        } else {
            for (int k = 0; k < 8; ++k) o[k] = (f16)0.f;
        }
        *reinterpret_cast<f16x8*>(w2p + i) = o;
    }
}

// ---------------- tg: pT[kc][16][1024] f32 partials of T = Wq @ W1 ----------------
__global__ __launch_bounds__(256) void tg_kernel(
    const float* __restrict__ Wq, const f16* __restrict__ W1t,
    float* __restrict__ pT)
{
    const int w = threadIdx.x >> 6, lane = threadIdx.x & 63;
    const int fr = lane & 15, fq = lane >> 4;
    const int kc = blockIdx.x & 15;
    const int et = blockIdx.x >> 4;
    const int e0 = et * 128 + w * 32;
    const int kbase = kc * 256;

    f32x4 acc[2] = {};
    #pragma unroll
    for (int s = 0; s < 8; ++s) {
        int k = kbase + s * 32 + fq * 8;
        float4 a0 = *reinterpret_cast<const float4*>(Wq + (size_t)fr * F_DIM + k);
        float4 a1 = *reinterpret_cast<const float4*>(Wq + (size_t)fr * F_DIM + k + 4);
        f16x8 af = cvt8(a0, a1);
        #pragma unroll
        for (int n = 0; n < 2; ++n) {
            f16x8 bf = *reinterpret_cast<const f16x8*>(W1t + (size_t)(e0 + n * 16 + fr) * F_DIM + k);
            acc[n] = __builtin_amdgcn_mfma_f32_16x16x32_f16(af, bf, acc[n], 0, 0, 0);
        }
    }
    #pragma unroll
    for (int n = 0; n < 2; ++n)
        #pragma unroll
        for (int j = 0; j < 4; ++j)
            pT[(size_t)kc * (16 * E_DIM) + (size_t)(fq * 4 + j) * E_DIM + e0 + n * 16 + fr] = acc[n][j];
}

// ---------------- treduce: Th[16][1024] f16 = sum_kc pT ----------------
__global__ __launch_bounds__(256) void treduce_kernel(
    const float* __restrict__ pT, f16* __restrict__ Th)
{
    int idx = blockIdx.x * 256 + threadIdx.x;
    float s = 0.f;
    #pragma unroll
    for (int kc = 0; kc < 16; ++kc) s += pT[(size_t)kc * (16 * E_DIM) + idx];
    Th[idx] = (f16)s;
}

// ---------------- qx2: qmp[8192][32] = cos(x @ Th^T + theta), fused (64 rows/block) ----------------
__global__ __launch_bounds__(512) void qx2_kernel(
    const float* __restrict__ x, const f16* __restrict__ Th,
    const float* __restrict__ theta, f16* __restrict__ qmp)
{
    __shared__ __align__(16) f16 ths[16 * 1024];
    __shared__ float pql[2048];             // [kc][64 rows][16 q]
    const int tid = threadIdx.x, w = tid >> 6, lane = tid & 63;
    const int fr = lane & 15, fq = lane >> 4;
    const int m0 = blockIdx.x * 64;

    #pragma unroll
    for (int i = 0; i < 4; ++i) {
        int tau = i * 512 + tid;            // 0..2047
        int q   = tau >> 7;
        int kb  = tau & 127;
        f16x8 v = *reinterpret_cast<const f16x8*>(Th + (size_t)q * E_DIM + kb * 8);
        int boff = (q * 2048 + kb * 16) ^ ((q & 7) << 4);
        *reinterpret_cast<f16x8*>((char*)ths + boff) = v;
    }
    __syncthreads();

    const int kc = w >> 2;
    const int rg = w & 3;
    const float* xa = x + (size_t)(m0 + rg * 16 + fr) * E_DIM + kc * 512;
    f32x4 acc = {};
    #pragma unroll
    for (int s = 0; s < 16; ++s) {
        int ko = s * 32 + fq * 8;
        float4 a0 = *reinterpret_cast<const float4*>(xa + ko);
        float4 a1 = *reinterpret_cast<const float4*>(xa + ko + 4);
        f16x8 af = cvt8(a0, a1);
        int boff = (fr * 2048 + (kc * 512 + ko) * 2) ^ ((fr & 7) << 4);
        f16x8 bf = *reinterpret_cast<const f16x8*>((char*)ths + boff);
        acc = __builtin_amdgcn_mfma_f32_16x16x32_f16(af, bf, acc, 0, 0, 0);
    }
    #pragma unroll
    for (int j = 0; j < 4; ++j)
        pql[(kc * 64 + rg * 16 + fq * 4 + j) * 16 + fr] = acc[j];
    __syncthreads();

    #pragma unroll
    for (int e = 0; e < 2; ++e) {
        int idx = e * 512 + tid;
        int row = idx >> 4, q = idx & 15;
        float s = pql[idx] + pql[1024 + idx];
        float v = cosf(s + theta[q]);
        qmp[(size_t)(m0 + row) * 32 + q]      = (f16)v;
        qmp[(size_t)(m0 + row) * 32 + 16 + q] = (f16)0.f;
    }
}

__device__ __forceinline__ void gload_lds16(const f16* g, f16* l) {
    __builtin_amdgcn_global_load_lds(
        (const __attribute__((address_space(1))) void*)(g),
        (__attribute__((address_space(3))) void*)(l), 16, 0, 0);
}

// ======== fused GEMM: out = relu(qm @ W2^T) @ Wo^T — 128x128 tile, BK=64, 8-phase ========
// 256 thr = 4 waves (2x2, each 64x64). NO split-K: grid 512 = 64 m x 8 n, K=4096,
// f32 out written directly. LDS 64KB (f16 units): buf b @ [b*16384,+16384) =
// { A[b] @ +0 (8192), B[b] @ +8192 (8192) } -> 2 blocks/CU resident.
// A produced in-kernel (r7-proven PRODUCE-in-STAGES form; PHASEP reverted).
__global__ __launch_bounds__(256, 2)
void gemm4f(const f16* __restrict__ qmp, const f16* __restrict__ w2g,
            const f16* __restrict__ woh, float* __restrict__ out)
{
    extern __shared__ __align__(16) f16 smem[];
    const int tid  = threadIdx.x;
    const int w    = tid >> 6;
    const int lane = tid & 63;

    const int nwg = gridDim.x;              // 512
    const int bid = blockIdx.x;
    const int cpx = nwg >> 3;               // 64
    int swz = (bid & 7) * cpx + (bid >> 3);
    const int by = swz & 63, bx = swz >> 6; // all blocks of one XCD share bx -> B-panel L2-hot
    const int m0 = by * 128, n0 = bx * 128;

    const int wr = w >> 1, wc = w & 1;
    const int fr = lane & 15, fq = lane >> 4;
    const int K = 4096;

    // ---- persistent q fragments (rows w*32+fr, +16) ----
    const int r0w = w * 32 + fr;
    f16x8 qreg0 = *reinterpret_cast<const f16x8*>(qmp + (size_t)(m0 + r0w) * 32 + fq * 8);
    f16x8 qreg1 = *reinterpret_cast<const f16x8*>(qmp + (size_t)(m0 + r0w + 16) * 32 + fq * 8);

    // ---- B staging: 4 gloads per buffer (32 rows each across 4 waves) ----
    const int rl   = tid >> 3;              // 0..31
    const int scol = ((lane & 7) ^ (rl & 7)) * 8;
    const f16* gB = woh + (size_t)(n0 + rl) * F_DIM + scol;
    f16* lBw = smem + 8192 + w * 512;       // + b*16384 + j*2048

#define SB(b,j,kt) gload_lds16(gB + (size_t)((j)*32) * F_DIM + (kt), lBw + (b)*16384 + (j)*2048)

    // ---- w2 fragment register loads ----
    f16x8 w2a[4], w2b[4];
#define LOADW2(R, kt) do { _Pragma("unroll") \
    for (int ft = 0; ft < 4; ++ft) \
        R[ft] = *reinterpret_cast<const f16x8*>(w2g + (size_t)((kt) + ft*16 + fr) * 32 + fq * 8); } while(0)

    // ---- produce A[bdst] = relu(qm @ w2[kt]^T), swizzled layout (r7 formulas) ----
#define PWRITE(bdst, ft, C0, C1) do {                                             \
    f16x4 h0_, h1_;                                                               \
    _Pragma("unroll") for (int jj = 0; jj < 4; ++jj) {                            \
        h0_[jj] = (f16)fmaxf(C0[jj], 0.f); h1_[jj] = (f16)fmaxf(C1[jj], 0.f); }   \
    const int sl_ = (2 * (ft) + (fq >> 1)) ^ (fr & 7);                            \
    *reinterpret_cast<f16x4*>(smem + (bdst)*16384 + (r0w)*64    + sl_*8 + ((fq & 1) << 2)) = h0_; \
    *reinterpret_cast<f16x4*>(smem + (bdst)*16384 + (r0w+16)*64 + sl_*8 + ((fq & 1) << 2)) = h1_; \
    } while(0)

#define PRODUCE(bdst, W2R) do {                                                   \
    f32x4 z_ = {0.f, 0.f, 0.f, 0.f};                                              \
    _Pragma("unroll") for (int ft = 0; ft < 4; ++ft) {                            \
        f32x4 c0_ = __builtin_amdgcn_mfma_f32_16x16x32_f16(W2R[ft], qreg0, z_, 0, 0, 0); \
        f32x4 c1_ = __builtin_amdgcn_mfma_f32_16x16x32_f16(W2R[ft], qreg1, z_, 0, 0, 0); \
        PWRITE(bdst, ft, c0_, c1_);                                               \
    } } while(0)

    // ---- fragment-read bases ----
    const int xm  = fr & 7;
    const int so0 = ((0 + fq) ^ xm) * 8;
    const int so1 = ((4 + fq) ^ xm) * 8;
    const int aro = (wr * 64 + fr) * 64;
    const int bro = (wc * 64 + fr) * 64;

#define AF(b,m,ks) (*reinterpret_cast<const f16x8*>(smem + (b)*16384 + aro + (m)*1024 + so##ks))
#define BF(b,n,ks) (*reinterpret_cast<const f16x8*>(smem + (b)*16384 + 8192 + bro + (n)*1024 + so##ks))

    f32x4 acc[4][4] = {};
    f16x8 bf[4][2];

#define PHASE(b, p, STAGES, W4) do {                                              \
    f16x8 a0 = AF(b, p, 0), a1 = AF(b, p, 1);                                     \
    if ((p) == 0) { _Pragma("unroll")                                             \
        for (int n = 0; n < 4; ++n) { bf[n][0] = BF(b,n,0); bf[n][1] = BF(b,n,1); } } \
    STAGES;                                                                       \
    BARRIER();                                                                    \
    __builtin_amdgcn_s_setprio(1);                                                \
    _Pragma("unroll") for (int n = 0; n < 4; ++n)                                 \
        acc[p][n] = __builtin_amdgcn_mfma_f32_16x16x32_f16(a0, bf[n][0], acc[p][n], 0,0,0); \
    _Pragma("unroll") for (int n = 0; n < 4; ++n)                                 \
        acc[p][n] = __builtin_amdgcn_mfma_f32_16x16x32_f16(a1, bf[n][1], acc[p][n], 0,0,0); \
    __builtin_amdgcn_s_setprio(0);                                                \
    if (W4) { WAITV(8); WAITLGKM(); }                                             \
    BARRIER(); } while(0)

    const int NT = K >> 6;      // 64 K-tiles
    const int NI = NT >> 1;     // 32 iters

    // prologue: q-frags + w2[t0],w2[t1] -> regs; B0<-t0, B1<-t1; produce A[0]<-t0
    LOADW2(w2b, 0);
    LOADW2(w2a, 64);
    SB(0,0,0);  SB(0,1,0);  SB(0,2,0);  SB(0,3,0);
    SB(1,0,64); SB(1,1,64); SB(1,2,64); SB(1,3,64);
    WAITV(0);
    BARRIER();
    PRODUCE(0, w2b);
    WAITLGKM();
    BARRIER();

    for (int i = 0; i < NI; ++i) {
        int t2 = 2*i+2; if (t2 > NT-1) t2 = NT-1;
        int t3 = 2*i+3; if (t3 > NT-1) t3 = NT-1;
        const int k2 = t2 << 6, k3 = t3 << 6;
        PHASE(0, 0, PRODUCE(1, w2a),                     0); // P1: produce A[1]<-t(2i+1)
        PHASE(0, 1, LOADW2(w2b, k2); SB(0,0,k2); SB(0,1,k2), 0); // P2
        PHASE(0, 2, SB(0,2,k2); SB(0,3,k2),              0); // P3
        PHASE(0, 3, ,                                    1); // P4: vmcnt(8)+lgkm(0)
        PHASE(1, 0, PRODUCE(0, w2b),                     0); // P5: produce A[0]<-t(2i+2)
        PHASE(1, 1, LOADW2(w2a, k3); SB(1,0,k3); SB(1,1,k3), 0); // P6
        PHASE(1, 2, SB(1,2,k3); SB(1,3,k3),              0); // P7
        PHASE(1, 3, ,                                    1); // P8: vmcnt(8)+lgkm(0)
    }
    WAITV(0);

    #pragma unroll
    for (int m = 0; m < 4; ++m) {
        #pragma unroll
        for (int n = 0; n < 4; ++n) {
            #pragma unroll
            for (int j = 0; j < 4; ++j) {
                int row = m0 + wr * 64 + m * 16 + fq * 4 + j;
                int col = n0 + wc * 64 + n * 16 + fr;
                out[(size_t)row * E_DIM + col] = acc[m][n][j];
            }
        }
    }
#undef SB
#undef LOADW2
#undef PWRITE
#undef PRODUCE
#undef AF
#undef BF
#undef PHASE
}

extern "C" void kernel_launch(void* const* d_in, const int* in_sizes, int n_in,
                              void* d_out, int out_size, void* d_ws, size_t ws_size,
                              hipStream_t stream) {
    const float* x  = (const float*)d_in[0];
    const float* W1 = (const float*)d_in[1];
    const float* Wq = (const float*)d_in[2];
    const float* th = (const float*)d_in[3];
    const float* W2 = (const float*)d_in[4];
    const float* Wo = (const float*)d_in[5];
    float* out = (float*)d_out;

    char* base = (char*)d_ws;
    float* pT  = (float*)base;                            // 1 MB (dead after treduce)
    f16*   Th  = (f16*)(base + (1 << 20));                // 32 KB (dead after qx2)
    f16*   w1t = (f16*)(base + 16777216);                 // 8.4 MB
    f16*   woh = w1t + (size_t)E_DIM * F_DIM;             // 8.4 MB
    f16*   w2p = woh + (size_t)E_DIM * F_DIM;             // 0.26 MB
    f16*   qmp = w2p + (size_t)F_DIM * 32;                // 0.52 MB

    static bool attr_done = false;
    if (!attr_done) {
        hipFuncSetAttribute((const void*)&gemm4f,
                            hipFuncAttributeMaxDynamicSharedMemorySize, 65536);
        attr_done = true;
    }

    // 1) prep (merged): W1 transpose-cast | Wo cast | W2 pad
    prep_kernel<<<3136, 256, 0, stream>>>(W1, w1t, Wo, woh, W2, w2p);
    // 2) T = Wq @ W1 -> Th f16 [16][1024]
    tg_kernel<<<128, 256, 0, stream>>>(Wq, w1t, pT);
    treduce_kernel<<<64, 256, 0, stream>>>(pT, Th);
    // 3) qmp = cos(x @ Th^T + theta), fused single kernel
    qx2_kernel<<<128, 512, 0, stream>>>(x, Th, th, qmp);
    // 4) fused: out = relu(qmp @ w2p^T) @ Wo^T — no split-K, f32 out direct
    gemm4f<<<512, 256, 65536, stream>>>(qmp, w2p, woh, out);
}

// Round 10
// 113.960 us; speedup vs baseline: 1.0402x; 1.0402x over previous
//
#include <hip/hip_runtime.h>
#include <hip/hip_bf16.h>
#include <math.h>

typedef _Float16 f16;
typedef __attribute__((ext_vector_type(8))) _Float16 f16x8;
typedef __attribute__((ext_vector_type(4))) _Float16 f16x4;
typedef __attribute__((ext_vector_type(4))) float f32x4;

#define M_TOT 8192      // BATCH*SEQ
#define E_DIM 1024
#define F_DIM 4096
#define NQ    16

#define BARRIER() asm volatile("s_barrier" ::: "memory")
#define WAITV(n)  asm volatile("s_waitcnt vmcnt(" #n ")" ::: "memory")
#define WAITLGKM() asm volatile("s_waitcnt lgkmcnt(0)" ::: "memory")

__device__ __forceinline__ f16x8 cvt8(float4 a, float4 b) {
    f16x8 o;
    o[0] = (f16)a.x; o[1] = (f16)a.y; o[2] = (f16)a.z; o[3] = (f16)a.w;
    o[4] = (f16)b.x; o[5] = (f16)b.y; o[6] = (f16)b.z; o[7] = (f16)b.w;
    return o;
}

// ---------------- merged prep: W1 transpose-cast | Wo cast | W2 pad ----------------
__global__ __launch_bounds__(256) void prep_kernel(
    const float* __restrict__ W1, f16* __restrict__ W1t,
    const float* __restrict__ wo, f16* __restrict__ woh,
    const float* __restrict__ W2, f16* __restrict__ w2p)
{
    __shared__ float ls[64][68];
    const int b = blockIdx.x;
    if (b < 1024) {
        const int bf = b & 63;
        const int be = b >> 6;
        const int t  = threadIdx.x;
        const int r  = t >> 4;
        const int c4 = (t & 15) * 4;
        #pragma unroll
        for (int i = 0; i < 4; ++i) {
            int fr = r + i * 16;
            float4 v = *reinterpret_cast<const float4*>(W1 + (size_t)(bf * 64 + fr) * E_DIM + be * 64 + c4);
            ls[fr][c4] = v.x; ls[fr][c4 + 1] = v.y; ls[fr][c4 + 2] = v.z; ls[fr][c4 + 3] = v.w;
        }
        __syncthreads();
        const int er = t >> 2;
        const int fc = (t & 3) * 16;
        f16x8 o0, o1;
        #pragma unroll
        for (int j = 0; j < 8; ++j) { o0[j] = (f16)ls[fc + j][er]; o1[j] = (f16)ls[fc + 8 + j][er]; }
        f16* dst = W1t + (size_t)(be * 64 + er) * F_DIM + bf * 64 + fc;
        *reinterpret_cast<f16x8*>(dst)     = o0;
        *reinterpret_cast<f16x8*>(dst + 8) = o1;
    } else if (b < 3072) {
        size_t i = ((size_t)(b - 1024) * 256 + threadIdx.x) * 8;
        float4 v0 = *reinterpret_cast<const float4*>(wo + i);
        float4 v1 = *reinterpret_cast<const float4*>(wo + i + 4);
        *reinterpret_cast<f16x8*>(woh + i) = cvt8(v0, v1);
    } else {
        int t = (b - 3072) * 256 + threadIdx.x;
        size_t i = (size_t)t * 8;
        int col = (int)(i & 31);
        f16x8 o;
        if (col < NQ) {
            int row = (int)(i >> 5);
            float4 v0 = *reinterpret_cast<const float4*>(W2 + (size_t)row * NQ + col);
            float4 v1 = *reinterpret_cast<const float4*>(W2 + (size_t)row * NQ + col + 4);
            o = cvt8(v0, v1);
        } else {
            for (int k = 0; k < 8; ++k) o[k] = (f16)0.f;
        }
        *reinterpret_cast<f16x8*>(w2p + i) = o;
    }
}

// ---------------- tg: pT[kc][16][1024] f32 partials of T = Wq @ W1 ----------------
__global__ __launch_bounds__(256) void tg_kernel(
    const float* __restrict__ Wq, const f16* __restrict__ W1t,
    float* __restrict__ pT)
{
    const int w = threadIdx.x >> 6, lane = threadIdx.x & 63;
    const int fr = lane & 15, fq = lane >> 4;
    const int kc = blockIdx.x & 15;
    const int et = blockIdx.x >> 4;
    const int e0 = et * 128 + w * 32;
    const int kbase = kc * 256;

    f32x4 acc[2] = {};
    #pragma unroll
    for (int s = 0; s < 8; ++s) {
        int k = kbase + s * 32 + fq * 8;
        float4 a0 = *reinterpret_cast<const float4*>(Wq + (size_t)fr * F_DIM + k);
        float4 a1 = *reinterpret_cast<const float4*>(Wq + (size_t)fr * F_DIM + k + 4);
        f16x8 af = cvt8(a0, a1);
        #pragma unroll
        for (int n = 0; n < 2; ++n) {
            f16x8 bf = *reinterpret_cast<const f16x8*>(W1t + (size_t)(e0 + n * 16 + fr) * F_DIM + k);
            acc[n] = __builtin_amdgcn_mfma_f32_16x16x32_f16(af, bf, acc[n], 0, 0, 0);
        }
    }
    #pragma unroll
    for (int n = 0; n < 2; ++n)
        #pragma unroll
        for (int j = 0; j < 4; ++j)
            pT[(size_t)kc * (16 * E_DIM) + (size_t)(fq * 4 + j) * E_DIM + e0 + n * 16 + fr] = acc[n][j];
}

// ---------------- treduce: Th[16][1024] f16 = sum_kc pT ----------------
__global__ __launch_bounds__(256) void treduce_kernel(
    const float* __restrict__ pT, f16* __restrict__ Th)
{
    int idx = blockIdx.x * 256 + threadIdx.x;
    float s = 0.f;
    #pragma unroll
    for (int kc = 0; kc < 16; ++kc) s += pT[(size_t)kc * (16 * E_DIM) + idx];
    Th[idx] = (f16)s;
}

// ---------------- qx2: qmp[8192][32] = cos(x @ Th^T + theta), fused (64 rows/block) ----------------
__global__ __launch_bounds__(512) void qx2_kernel(
    const float* __restrict__ x, const f16* __restrict__ Th,
    const float* __restrict__ theta, f16* __restrict__ qmp)
{
    __shared__ __align__(16) f16 ths[16 * 1024];
    __shared__ float pql[2048];             // [kc][64 rows][16 q]
    const int tid = threadIdx.x, w = tid >> 6, lane = tid & 63;
    const int fr = lane & 15, fq = lane >> 4;
    const int m0 = blockIdx.x * 64;

    #pragma unroll
    for (int i = 0; i < 4; ++i) {
        int tau = i * 512 + tid;            // 0..2047
        int q   = tau >> 7;
        int kb  = tau & 127;
        f16x8 v = *reinterpret_cast<const f16x8*>(Th + (size_t)q * E_DIM + kb * 8);
        int boff = (q * 2048 + kb * 16) ^ ((q & 7) << 4);
        *reinterpret_cast<f16x8*>((char*)ths + boff) = v;
    }
    __syncthreads();

    const int kc = w >> 2;
    const int rg = w & 3;
    const float* xa = x + (size_t)(m0 + rg * 16 + fr) * E_DIM + kc * 512;
    f32x4 acc = {};
    #pragma unroll
    for (int s = 0; s < 16; ++s) {
        int ko = s * 32 + fq * 8;
        float4 a0 = *reinterpret_cast<const float4*>(xa + ko);
        float4 a1 = *reinterpret_cast<const float4*>(xa + ko + 4);
        f16x8 af = cvt8(a0, a1);
        int boff = (fr * 2048 + (kc * 512 + ko) * 2) ^ ((fr & 7) << 4);
        f16x8 bf = *reinterpret_cast<const f16x8*>((char*)ths + boff);
        acc = __builtin_amdgcn_mfma_f32_16x16x32_f16(af, bf, acc, 0, 0, 0);
    }
    #pragma unroll
    for (int j = 0; j < 4; ++j)
        pql[(kc * 64 + rg * 16 + fq * 4 + j) * 16 + fr] = acc[j];
    __syncthreads();

    #pragma unroll
    for (int e = 0; e < 2; ++e) {
        int idx = e * 512 + tid;
        int row = idx >> 4, q = idx & 15;
        float s = pql[idx] + pql[1024 + idx];
        float v = cosf(s + theta[q]);
        qmp[(size_t)(m0 + row) * 32 + q]      = (f16)v;
        qmp[(size_t)(m0 + row) * 32 + 16 + q] = (f16)0.f;
    }
}

__device__ __forceinline__ void gload_lds16(const f16* g, f16* l) {
    __builtin_amdgcn_global_load_lds(
        (const __attribute__((address_space(1))) void*)(g),
        (__attribute__((address_space(3))) void*)(l), 16, 0, 0);
}

// ================= fused GEMM: out = relu(qm @ W2^T) @ Wo^T, 256x256 8-phase =================
// EXACT round-7-measured structure (80.4 us): PRODUCE in STAGES slot, persistent q-regs,
// split-K=2, f16 partials. LDS (f16 units): buf b @ [b*32768,+32768) = { A[b] @ +0,
// B[b] @ +16384 }. Total 131072 B.
__global__ __launch_bounds__(512, 2)
void gemm4f(const f16* __restrict__ qmp, const f16* __restrict__ w2p,
            const f16* __restrict__ Wo, f16* __restrict__ P0, f16* __restrict__ P1)
{
    extern __shared__ __align__(16) f16 smem[];
    const int tid  = threadIdx.x;
    const int w    = tid >> 6;
    const int lane = tid & 63;

    const int nwg = gridDim.x;              // 256
    const int bid = blockIdx.x;
    const int cpx = nwg >> 3;
    int swz = (bid & 7) * cpx + (bid >> 3);
    const int per = nwg >> 1;               // 128
    const int split = swz / per;
    const int r = swz % per;
    const int by = r >> 2, bx = r & 3;      // gx = 4
    const int m0 = by * 256, n0 = bx * 256;

    const int wr = w >> 2, wc = w & 3;
    const int fr = lane & 15, fq = lane >> 4;
    const int K = 2048;                     // per split

    const f16* Bb  = Wo + (size_t)split * K;
    const f16* w2g = w2p + (size_t)split * K * 32;
    f16* Pout = split ? P1 : P0;

    // ---- persistent q fragments ----
    const int r0w = w * 32 + fr;
    f16x8 qreg0 = *reinterpret_cast<const f16x8*>(qmp + (size_t)(m0 + r0w) * 32 + fq * 8);
    f16x8 qreg1 = *reinterpret_cast<const f16x8*>(qmp + (size_t)(m0 + r0w + 16) * 32 + fq * 8);

    // ---- B staging ----
    const int rl   = w * 8 + (lane >> 3);
    const int scol = (((lane & 7) ^ (rl & 7)) * 8);
    const f16* gB = Bb + (size_t)(n0 + rl) * F_DIM + scol;
    f16* lB = smem + 16384 + w * 512;

#define SB(b,h,j,kt) gload_lds16(gB + (size_t)((h)*128 + (j)*64) * F_DIM + (kt), lB + (b)*32768 + (h)*8192 + (j)*4096)
#define SBH(b,h,kt) do { SB(b,h,0,kt); SB(b,h,1,kt); } while(0)

    // ---- w2 fragment register loads ----
    f16x8 w2a[4], w2b[4];
#define LOADW2(R, kt) do { _Pragma("unroll") \
    for (int ft = 0; ft < 4; ++ft) \
        R[ft] = *reinterpret_cast<const f16x8*>(w2g + (size_t)((kt) + ft*16 + fr) * 32 + fq * 8); } while(0)

    // ---- produce A[bdst] = relu(qm @ w2[kt]^T) in swizzled layout (all-register inputs) ----
#define PRODUCE(bdst, W2R) do {                                                   \
    f32x4 z_ = {0.f, 0.f, 0.f, 0.f};                                              \
    _Pragma("unroll") for (int ft = 0; ft < 4; ++ft) {                            \
        f32x4 c0_ = __builtin_amdgcn_mfma_f32_16x16x32_f16(W2R[ft], qreg0, z_, 0, 0, 0); \
        f32x4 c1_ = __builtin_amdgcn_mfma_f32_16x16x32_f16(W2R[ft], qreg1, z_, 0, 0, 0); \
        f16x4 h0_, h1_;                                                           \
        _Pragma("unroll") for (int jj = 0; jj < 4; ++jj) {                        \
            h0_[jj] = (f16)fmaxf(c0_[jj], 0.f); h1_[jj] = (f16)fmaxf(c1_[jj], 0.f); } \
        const int sl_ = (2 * ft + (fq >> 1)) ^ (fr & 7);                          \
        *reinterpret_cast<f16x4*>(smem + (bdst)*32768 + (r0w)*64      + sl_*8 + ((fq & 1) << 2)) = h0_; \
        *reinterpret_cast<f16x4*>(smem + (bdst)*32768 + (r0w+16)*64   + sl_*8 + ((fq & 1) << 2)) = h1_; \
    } } while(0)

    // ---- main fragment-read bases ----
    const int xm  = fr & 7;
    const int so0 = ((0 + fq) ^ xm) * 8;
    const int so1 = ((4 + fq) ^ xm) * 8;
    const int aro = (wr * 128 + fr) * 64;
    const int bro = (wc * 64  + fr) * 64;

#define AF(b,m,ks) (*reinterpret_cast<const f16x8*>(smem + (b)*32768 + aro + (m)*1024 + so##ks))
#define BF(b,n,ks) (*reinterpret_cast<const f16x8*>(smem + (b)*32768 + 16384 + bro + (n)*1024 + so##ks))

    f32x4 acc[8][4] = {};
    f16x8 bf[4][2];

#define PHASE(b, p, STAGES, W4) do {                                              \
    f16x8 a00 = AF(b, 2*(p),   0), a01 = AF(b, 2*(p),   1);                       \
    f16x8 a10 = AF(b, 2*(p)+1, 0), a11 = AF(b, 2*(p)+1, 1);                       \
    if ((p) == 0) { _Pragma("unroll")                                             \
        for (int n = 0; n < 4; ++n) { bf[n][0] = BF(b,n,0); bf[n][1] = BF(b,n,1); } } \
    STAGES;                                                                       \
    BARRIER();                                                                    \
    __builtin_amdgcn_s_setprio(1);                                                \
    _Pragma("unroll") for (int n = 0; n < 4; ++n) {                               \
        acc[2*(p)  ][n] = __builtin_amdgcn_mfma_f32_16x16x32_f16(a00, bf[n][0], acc[2*(p)  ][n], 0,0,0); \
        acc[2*(p)+1][n] = __builtin_amdgcn_mfma_f32_16x16x32_f16(a10, bf[n][0], acc[2*(p)+1][n], 0,0,0); } \
    _Pragma("unroll") for (int n = 0; n < 4; ++n) {                               \
        acc[2*(p)  ][n] = __builtin_amdgcn_mfma_f32_16x16x32_f16(a01, bf[n][1], acc[2*(p)  ][n], 0,0,0); \
        acc[2*(p)+1][n] = __builtin_amdgcn_mfma_f32_16x16x32_f16(a11, bf[n][1], acc[2*(p)+1][n], 0,0,0); } \
    __builtin_amdgcn_s_setprio(0);                                                \
    if (W4) { WAITV(8); WAITLGKM(); }                                             \
    BARRIER(); } while(0)

    const int NT = K >> 6;      // 32
    const int NI = NT >> 1;     // 16

    // prologue: q-frags + w2[k0],w2[k1] -> regs; B0<-k0, B1<-k1; produce A[0]
    LOADW2(w2b, 0);
    LOADW2(w2a, 64);
    SBH(0,0,0);  SBH(0,1,0);
    SBH(1,0,64); SBH(1,1,64);
    WAITV(0);
    BARRIER();
    PRODUCE(0, w2b);
    WAITLGKM();
    BARRIER();

    for (int i = 0; i < NI; ++i) {
        int t2 = 2*i+2; if (t2 > NT-1) t2 = NT-1;
        int t3 = 2*i+3; if (t3 > NT-1) t3 = NT-1;
        const int k2 = t2 << 6, k3 = t3 << 6;
        PHASE(0, 0, PRODUCE(1, w2a),            0);   // P1: produce A[1]<-k1
        PHASE(0, 1, LOADW2(w2b, k2); SBH(0,0,k2), 0); // P2
        PHASE(0, 2, SBH(0,1,k2),                0);   // P3
        PHASE(0, 3, ,                           1);   // P4: vmcnt(8)+lgkm(0)
        PHASE(1, 0, PRODUCE(0, w2b),            0);   // P5: produce A[0]<-k2
        PHASE(1, 1, LOADW2(w2a, k3); SBH(1,0,k3), 0); // P6
        PHASE(1, 2, SBH(1,1,k3),                0);   // P7
        PHASE(1, 3, ,                           1);   // P8: vmcnt(8)+lgkm(0)
    }
    WAITV(0);

    #pragma unroll
    for (int m = 0; m < 8; ++m) {
        #pragma unroll
        for (int n = 0; n < 4; ++n) {
            #pragma unroll
            for (int j = 0; j < 4; ++j) {
                int row = m0 + wr * 128 + m * 16 + fq * 4 + j;
                int col = n0 + wc * 64  + n * 16 + fr;
                Pout[(size_t)row * E_DIM + col] = (f16)acc[m][n][j];
            }
        }
    }
#undef SB
#undef SBH
#undef LOADW2
#undef PRODUCE
#undef AF
#undef BF
#undef PHASE
}

// ---------------- out = (float)p0 + (float)p1 ----------------
__global__ __launch_bounds__(256) void out_reduce2_kernel(
    float* __restrict__ out, const f16* __restrict__ p0, const f16* __restrict__ p1)
{
    size_t i = ((size_t)blockIdx.x * 256 + threadIdx.x) * 8;
    f16x8 a = *reinterpret_cast<const f16x8*>(p0 + i);
    f16x8 b = *reinterpret_cast<const f16x8*>(p1 + i);
    float4 v0, v1;
    v0.x = (float)a[0] + (float)b[0]; v0.y = (float)a[1] + (float)b[1];
    v0.z = (float)a[2] + (float)b[2]; v0.w = (float)a[3] + (float)b[3];
    v1.x = (float)a[4] + (float)b[4]; v1.y = (float)a[5] + (float)b[5];
    v1.z = (float)a[6] + (float)b[6]; v1.w = (float)a[7] + (float)b[7];
    *reinterpret_cast<float4*>(out + i)     = v0;
    *reinterpret_cast<float4*>(out + i + 4) = v1;
}

extern "C" void kernel_launch(void* const* d_in, const int* in_sizes, int n_in,
                              void* d_out, int out_size, void* d_ws, size_t ws_size,
                              hipStream_t stream) {
    const float* x  = (const float*)d_in[0];
    const float* W1 = (const float*)d_in[1];
    const float* Wq = (const float*)d_in[2];
    const float* th = (const float*)d_in[3];
    const float* W2 = (const float*)d_in[4];
    const float* Wo = (const float*)d_in[5];
    float* out = (float*)d_out;

    char* base = (char*)d_ws;
    float* pT  = (float*)base;                            // 1 MB (dead after treduce)
    f16*   Th  = (f16*)(base + (1 << 20));                // 32 KB (dead after qx2)
    f16*   w1t = (f16*)(base + 16777216);                 // 8.4 MB
    f16*   woh = w1t + (size_t)E_DIM * F_DIM;             // 8.4 MB
    f16*   w2p = woh + (size_t)E_DIM * F_DIM;             // 0.26 MB
    f16*   qmp = w2p + (size_t)F_DIM * 32;                // 0.52 MB
    f16*   p0  = qmp + (size_t)M_TOT * 32;                // 16.8 MB
    f16*   p1  = p0  + (size_t)M_TOT * E_DIM;             // 16.8 MB

    static bool attr_done = false;
    if (!attr_done) {
        hipFuncSetAttribute((const void*)&gemm4f,
                            hipFuncAttributeMaxDynamicSharedMemorySize, 131072);
        attr_done = true;
    }

    // 1) prep (merged): W1 transpose-cast | Wo cast | W2 pad
    prep_kernel<<<3136, 256, 0, stream>>>(W1, w1t, Wo, woh, W2, w2p);
    // 2) T = Wq @ W1 -> Th f16 [16][1024]
    tg_kernel<<<128, 256, 0, stream>>>(Wq, w1t, pT);
    treduce_kernel<<<64, 256, 0, stream>>>(pT, Th);
    // 3) qmp = cos(x @ Th^T + theta), fused single kernel
    qx2_kernel<<<128, 512, 0, stream>>>(x, Th, th, qmp);
    // 4) fused: out-partials = relu(qmp @ w2p^T) @ Wo^T, split-K=2, f16 partials
    gemm4f<<<256, 512, 131072, stream>>>(qmp, w2p, woh, p0, p1);
    // 5) out = p0 + p1
    out_reduce2_kernel<<<4096, 256, 0, stream>>>(out, p0, p1);
}